// Round 2
// baseline (152.136 us; speedup 1.0000x reference)
//
#include <hip/hip_runtime.h>
#include <hip/hip_bf16.h>
#include <math.h>

#define N_ROWS 4096
#define DIM    512
#define M_ROWS 8192
// sim GEMM: 256x256 tiles, BK=64, 8 waves (2 M x 4 N), per-wave 128x64 output
#define NTILE  32            // 8192 / 256
#define NB     528           // 32*33/2 triangular tiles (528 % 8 == 0)
#define NKT    8             // 512 / 64
// exp(sim/0.1) = exp2(sim * 10*log2(e))
#define EXP_SCALE 14.4269504088896340736f

typedef unsigned short ushort_t;
typedef __attribute__((ext_vector_type(8))) short short8;
typedef __attribute__((ext_vector_type(4))) float f32x4;

__device__ __forceinline__ ushort_t f2bf(float x) {
  unsigned int bits = __float_as_uint(x);
  unsigned int lsb = (bits >> 16) & 1u;
  bits += 0x7fffu + lsb;
  return (ushort_t)(bits >> 16);
}

__device__ __forceinline__ void store4bf(ushort_t* p, float4 v, float s) {
  union { ushort_t u[4]; uint2 d; } pk;
  pk.u[0] = f2bf(v.x * s);
  pk.u[1] = f2bf(v.y * s);
  pk.u[2] = f2bf(v.z * s);
  pk.u[3] = f2bf(v.w * s);
  *(uint2*)p = pk.d;
}

// async global -> LDS, 16 B/lane (lds dest = wave-uniform base + lane*16)
__device__ __forceinline__ void async16(const ushort_t* g, ushort_t* l) {
  __builtin_amdgcn_global_load_lds(
      (const __attribute__((address_space(1))) void*)g,
      (__attribute__((address_space(3))) void*)l,
      16, 0, 0);
}

// ---------------------------------------------------------------------------
// Kernel 1: per-row L2 normalize; 256-thread blocks, one wave per row-pair.
// Also zeroes denom[].
// ---------------------------------------------------------------------------
__global__ __launch_bounds__(256) void norm_kernel(
    const float* __restrict__ ei, const float* __restrict__ ej,
    ushort_t* __restrict__ reps, float* __restrict__ pos,
    float* __restrict__ denom) {
  int wave = threadIdx.x >> 6;
  int lane = threadIdx.x & 63;
  int b = blockIdx.x * 4 + wave;
  if (lane == 0) {
    denom[b] = 0.0f;
    denom[b + N_ROWS] = 0.0f;
  }
  const float4* pi = (const float4*)(ei + (size_t)b * DIM);
  const float4* pj = (const float4*)(ej + (size_t)b * DIM);
  float4 a0 = pi[lane];
  float4 a1 = pi[lane + 64];
  float4 b0 = pj[lane];
  float4 b1 = pj[lane + 64];

  float si = a0.x*a0.x + a0.y*a0.y + a0.z*a0.z + a0.w*a0.w
           + a1.x*a1.x + a1.y*a1.y + a1.z*a1.z + a1.w*a1.w;
  float sj = b0.x*b0.x + b0.y*b0.y + b0.z*b0.z + b0.w*b0.w
           + b1.x*b1.x + b1.y*b1.y + b1.z*b1.z + b1.w*b1.w;
  float dp = a0.x*b0.x + a0.y*b0.y + a0.z*b0.z + a0.w*b0.w
           + a1.x*b1.x + a1.y*b1.y + a1.z*b1.z + a1.w*b1.w;

#pragma unroll
  for (int m = 32; m >= 1; m >>= 1) {
    si += __shfl_xor(si, m, 64);
    sj += __shfl_xor(sj, m, 64);
    dp += __shfl_xor(dp, m, 64);
  }
  float ii = 1.0f / fmaxf(sqrtf(si), 1e-12f);
  float ij = 1.0f / fmaxf(sqrtf(sj), 1e-12f);
  if (lane == 0) pos[b] = dp * ii * ij;

  ushort_t* ri = reps + (size_t)b * DIM;
  ushort_t* rj = reps + (size_t)(b + N_ROWS) * DIM;
  store4bf(ri + lane * 4,       a0, ii);
  store4bf(ri + 256 + lane * 4, a1, ii);
  store4bf(rj + lane * 4,       b0, ij);
  store4bf(rj + 256 + lane * 4, b1, ij);
}

// ---------------------------------------------------------------------------
// Kernel 2: 256x256-tile fused sim-GEMM + exp + masked row/col reduction.
// Rationale: the 128^2 version moved 532 MB of operand traffic at ~7 TB/s
// (= its whole 77 us). 256^2 halves traffic to 270 MB. m201-geometry:
// 8 waves (2Mx4N), BK=64, 128 KiB LDS double-buffer, acc[8][4].
// Schedule per K-tile: stage next tile (8 x global_load_lds w16, swizzled
// source) -> 16 ds_read (b + first two m-pairs) -> 4 barrier-phased 16-MFMA
// clusters with a-frag read-ahead -> vmcnt(0)+barrier boundary (drain is
// covered by a full tile of MFMA).
// LDS swizzle: byte ^= (row&7)<<4 on both sides (linear gload_lds dest +
// pre-swizzled global source; swizzled ds_read) -> conflict-free at 128 B
// row pitch.
// ---------------------------------------------------------------------------
__global__ __launch_bounds__(512, 2) void sim_kernel(
    const ushort_t* __restrict__ reps, float* __restrict__ denom) {
  // triangular block id, XCD-swizzled (528 = 8 * 66, exact -> bijective)
  int id = blockIdx.x;
  id = (id & 7) * (NB / 8) + (id >> 3);
  int bj = (int)((sqrtf(8.0f * (float)id + 1.0f) - 1.0f) * 0.5f);
  while ((bj + 1) * (bj + 2) / 2 <= id) ++bj;
  while (bj * (bj + 1) / 2 > id) --bj;
  int bi = id - bj * (bj + 1) / 2;   // 0 <= bi <= bj < 32

  // [dbuf][half(128 rows)][128*64 bf16] ; 64 KB + 64 KB = 128 KB
  __shared__ ushort_t As[2][2][128 * 64];
  __shared__ ushort_t Bs[2][2][128 * 64];

  int tid  = threadIdx.x;
  int wave = tid >> 6, lane = tid & 63;
  int wr = wave >> 2, wc = wave & 3;       // 2 x 4 wave grid
  int hb = wc >> 1;                        // B half this wave consumes
  int q = lane >> 4, l15 = lane & 15;

  // ---- staging map: chunk (wave + 8i) covers rows chunk*8..+7 of a half ----
  int srow = lane >> 3;                        // row within 8-row chunk
  int scol = ((lane & 7) ^ srow) * 8;          // pre-swizzled global col (elems)
  const ushort_t* pA0 = reps + (size_t)(bi * 256 + wave * 8 + srow) * DIM + scol;
  const ushort_t* pA1 = pA0 + (size_t)128 * DIM;
  const ushort_t* pB0 = reps + (size_t)(bj * 256 + wave * 8 + srow) * DIM + scol;
  const ushort_t* pB1 = pB0 + (size_t)128 * DIM;

#define STAGE_TILE(D, KOFF) do {                                   \
    ushort_t* la0 = &As[D][0][wave * 512];                         \
    ushort_t* la1 = &As[D][1][wave * 512];                         \
    ushort_t* lb0 = &Bs[D][0][wave * 512];                         \
    ushort_t* lb1 = &Bs[D][1][wave * 512];                         \
    async16(pA0 + (KOFF),            la0);                         \
    async16(pA0 + 64 * DIM + (KOFF), la0 + 4096);                  \
    async16(pA1 + (KOFF),            la1);                         \
    async16(pA1 + 64 * DIM + (KOFF), la1 + 4096);                  \
    async16(pB0 + (KOFF),            lb0);                         \
    async16(pB0 + 64 * DIM + (KOFF), lb0 + 4096);                  \
    async16(pB1 + (KOFF),            lb1);                         \
    async16(pB1 + 64 * DIM + (KOFF), lb1 + 4096);                  \
  } while (0)

  // ---- fragment read offsets (elems), swizzle slot ^= (row&7) ----
  int axor = l15 & 7;
  int aoff0 = l15 * 64 + ((q ^ axor) * 8);          // ks = 0
  int aoff1 = l15 * 64 + (((4 + q) ^ axor) * 8);    // ks = 1
  int boff0 = (wc & 1) * 4096 + aoff0;
  int boff1 = (wc & 1) * 4096 + aoff1;

  f32x4 zero4 = {0.0f, 0.0f, 0.0f, 0.0f};
  f32x4 acc[8][4];
#pragma unroll
  for (int m = 0; m < 8; ++m)
#pragma unroll
    for (int n = 0; n < 4; ++n) acc[m][n] = zero4;

#define READ_A(DST, MB) do {                                       \
    DST[0][0] = *(const short8*)(Ah + (MB) * 1024 + aoff0);        \
    DST[0][1] = *(const short8*)(Ah + (MB) * 1024 + aoff1);        \
    DST[1][0] = *(const short8*)(Ah + (MB + 1) * 1024 + aoff0);    \
    DST[1][1] = *(const short8*)(Ah + (MB + 1) * 1024 + aoff1);    \
  } while (0)

#define MFMA_PH(MB, AF) do {                                                          \
    _Pragma("unroll")                                                                 \
    for (int n = 0; n < 4; ++n) {                                                     \
      acc[MB][n] = __builtin_amdgcn_mfma_f32_16x16x32_bf16(                           \
          AF[0][0], bfr[0][n], acc[MB][n], 0, 0, 0);                                  \
      acc[MB][n] = __builtin_amdgcn_mfma_f32_16x16x32_bf16(                           \
          AF[0][1], bfr[1][n], acc[MB][n], 0, 0, 0);                                  \
      acc[MB + 1][n] = __builtin_amdgcn_mfma_f32_16x16x32_bf16(                       \
          AF[1][0], bfr[0][n], acc[MB + 1][n], 0, 0, 0);                              \
      acc[MB + 1][n] = __builtin_amdgcn_mfma_f32_16x16x32_bf16(                       \
          AF[1][1], bfr[1][n], acc[MB + 1][n], 0, 0, 0);                              \
    }                                                                                 \
  } while (0)

  // prologue: stage K-tile 0
  STAGE_TILE(0, 0);
  asm volatile("s_waitcnt vmcnt(0)" ::: "memory");
  __builtin_amdgcn_s_barrier();

  for (int kt = 0; kt < NKT; ++kt) {
    int cur = kt & 1;
    const ushort_t* Ah = &As[cur][wr][0];
    const ushort_t* Bh = &Bs[cur][hb][0];

    if (kt < NKT - 1) STAGE_TILE(cur ^ 1, (kt + 1) * 64);

    short8 bfr[2][4];
#pragma unroll
    for (int n = 0; n < 4; ++n) {
      bfr[0][n] = *(const short8*)(Bh + n * 1024 + boff0);
      bfr[1][n] = *(const short8*)(Bh + n * 1024 + boff1);
    }
    short8 aX[2][2], aY[2][2];
    READ_A(aX, 0);
    READ_A(aY, 2);

    __builtin_amdgcn_s_barrier();
    __builtin_amdgcn_s_setprio(1);
    MFMA_PH(0, aX);
    __builtin_amdgcn_s_setprio(0);
    READ_A(aX, 4);

    __builtin_amdgcn_s_barrier();
    __builtin_amdgcn_s_setprio(1);
    MFMA_PH(2, aY);
    __builtin_amdgcn_s_setprio(0);
    READ_A(aY, 6);

    __builtin_amdgcn_s_barrier();
    __builtin_amdgcn_s_setprio(1);
    MFMA_PH(4, aX);
    __builtin_amdgcn_s_setprio(0);

    __builtin_amdgcn_s_barrier();
    __builtin_amdgcn_s_setprio(1);
    MFMA_PH(6, aY);
    __builtin_amdgcn_s_setprio(0);

    // tile boundary: next tile's staging (issued a full tile of MFMA ago)
    // must be LDS-visible to all waves before anyone reads it
    asm volatile("s_waitcnt vmcnt(0)" ::: "memory");
    __builtin_amdgcn_s_barrier();
  }

  // ---- epilogue: e = exp(sim/T), mask diagonal, row + col sums ----
  // C layout per 16x16 frag: col = l15, row = q*4 + r  [m89/m91]
  int rowb = bi * 256 + wr * 128 + q * 4;   // + m*16 + r
  int colb = bj * 256 + wc * 64 + l15;      // + n*16
  bool diag = (bi == bj);

  float rsum[8][4];
  float csum[4] = {0.0f, 0.0f, 0.0f, 0.0f};
#pragma unroll
  for (int m = 0; m < 8; ++m)
#pragma unroll
    for (int r = 0; r < 4; ++r) rsum[m][r] = 0.0f;

#pragma unroll
  for (int m = 0; m < 8; ++m) {
#pragma unroll
    for (int n = 0; n < 4; ++n) {
      f32x4 a = acc[m][n];
#pragma unroll
      for (int r = 0; r < 4; ++r) {
        float v = exp2f(a[r] * EXP_SCALE);
        if (diag && (rowb + m * 16 + r) == (colb + n * 16)) v = 0.0f;
        rsum[m][r] += v;
        csum[n] += v;
      }
    }
  }

  // row sums: reduce across l15 (masks 1,2,4,8)
#pragma unroll
  for (int m = 0; m < 8; ++m)
#pragma unroll
    for (int r = 0; r < 4; ++r) {
      float v = rsum[m][r];
      v += __shfl_xor(v, 1, 64);
      v += __shfl_xor(v, 2, 64);
      v += __shfl_xor(v, 4, 64);
      v += __shfl_xor(v, 8, 64);
      if (l15 == 0) atomicAdd(&denom[rowb + m * 16 + r], v);
    }

  if (!diag) {
    // col sums: reduce across q (masks 16,32)
#pragma unroll
    for (int n = 0; n < 4; ++n) {
      float v = csum[n];
      v += __shfl_xor(v, 16, 64);
      v += __shfl_xor(v, 32, 64);
      if (q == 0) atomicAdd(&denom[colb + n * 16], v);
    }
  }
}

// ---------------------------------------------------------------------------
// Kernel 3: loss = mean over rows of [log(denom) - pos/T]
// ---------------------------------------------------------------------------
__global__ __launch_bounds__(256) void loss_kernel(
    const float* __restrict__ denom, const float* __restrict__ pos,
    float* __restrict__ out) {
  __shared__ float red[4];
  int tid = threadIdx.x;
  float p = 0.0f;
  for (int r = tid; r < M_ROWS; r += 256)
    p += logf(denom[r]) - pos[r & (N_ROWS - 1)] * 10.0f;
#pragma unroll
  for (int m = 32; m >= 1; m >>= 1) p += __shfl_xor(p, m, 64);
  if ((tid & 63) == 0) red[tid >> 6] = p;
  __syncthreads();
  if (tid == 0)
    out[0] = (red[0] + red[1] + red[2] + red[3]) * (1.0f / M_ROWS);
}

extern "C" void kernel_launch(void* const* d_in, const int* in_sizes, int n_in,
                              void* d_out, int out_size, void* d_ws, size_t ws_size,
                              hipStream_t stream) {
  const float* ei = (const float*)d_in[0];
  const float* ej = (const float*)d_in[1];
  float* out = (float*)d_out;

  char* ws = (char*)d_ws;
  ushort_t* reps = (ushort_t*)ws;                                   // 8 MB bf16
  float* denom = (float*)(ws + (size_t)M_ROWS * DIM * 2);           // 32 KB
  float* pos = (float*)(ws + (size_t)M_ROWS * DIM * 2 + M_ROWS * 4);// 16 KB

  norm_kernel<<<N_ROWS / 4, 256, 0, stream>>>(ei, ej, reps, pos, denom);
  sim_kernel<<<NB, 512, 0, stream>>>(reps, denom);
  loss_kernel<<<1, 256, 0, stream>>>(denom, pos, out);
}

// Round 3
// 148.929 us; speedup vs baseline: 1.0215x; 1.0215x over previous
//
#include <hip/hip_runtime.h>
#include <hip/hip_bf16.h>
#include <math.h>

#define N_ROWS 4096
#define DIM    512
#define M_ROWS 8192
// sim GEMM: 256x256 tiles, BK=64, 8 waves (2 M x 4 N), per-wave 128x64 output
#define NTILE  32            // 8192 / 256
#define NB     528           // 32*33/2 triangular tiles (528 % 8 == 0)
#define NKT    8             // 512 / 64
// exp(sim/0.1) = exp2(sim * 10*log2(e))
#define EXP_SCALE 14.4269504088896340736f

typedef unsigned short ushort_t;
typedef __attribute__((ext_vector_type(8))) short short8;
typedef __attribute__((ext_vector_type(4))) float f32x4;

__device__ __forceinline__ ushort_t f2bf(float x) {
  unsigned int bits = __float_as_uint(x);
  unsigned int lsb = (bits >> 16) & 1u;
  bits += 0x7fffu + lsb;
  return (ushort_t)(bits >> 16);
}

__device__ __forceinline__ void store4bf(ushort_t* p, float4 v, float s) {
  union { ushort_t u[4]; uint2 d; } pk;
  pk.u[0] = f2bf(v.x * s);
  pk.u[1] = f2bf(v.y * s);
  pk.u[2] = f2bf(v.z * s);
  pk.u[3] = f2bf(v.w * s);
  *(uint2*)p = pk.d;
}

// async global -> LDS, 16 B/lane (lds dest = wave-uniform base + lane*16)
__device__ __forceinline__ void async16(const ushort_t* g, ushort_t* l) {
  __builtin_amdgcn_global_load_lds(
      (const __attribute__((address_space(1))) void*)g,
      (__attribute__((address_space(3))) void*)l,
      16, 0, 0);
}

// ---------------------------------------------------------------------------
// Kernel 1: per-row L2 normalize; 256-thread blocks, one wave per row-pair.
// Also zeroes denom[].
// ---------------------------------------------------------------------------
__global__ __launch_bounds__(256) void norm_kernel(
    const float* __restrict__ ei, const float* __restrict__ ej,
    ushort_t* __restrict__ reps, float* __restrict__ pos,
    float* __restrict__ denom) {
  int wave = threadIdx.x >> 6;
  int lane = threadIdx.x & 63;
  int b = blockIdx.x * 4 + wave;
  if (lane == 0) {
    denom[b] = 0.0f;
    denom[b + N_ROWS] = 0.0f;
  }
  const float4* pi = (const float4*)(ei + (size_t)b * DIM);
  const float4* pj = (const float4*)(ej + (size_t)b * DIM);
  float4 a0 = pi[lane];
  float4 a1 = pi[lane + 64];
  float4 b0 = pj[lane];
  float4 b1 = pj[lane + 64];

  float si = a0.x*a0.x + a0.y*a0.y + a0.z*a0.z + a0.w*a0.w
           + a1.x*a1.x + a1.y*a1.y + a1.z*a1.z + a1.w*a1.w;
  float sj = b0.x*b0.x + b0.y*b0.y + b0.z*b0.z + b0.w*b0.w
           + b1.x*b1.x + b1.y*b1.y + b1.z*b1.z + b1.w*b1.w;
  float dp = a0.x*b0.x + a0.y*b0.y + a0.z*b0.z + a0.w*b0.w
           + a1.x*b1.x + a1.y*b1.y + a1.z*b1.z + a1.w*b1.w;

#pragma unroll
  for (int m = 32; m >= 1; m >>= 1) {
    si += __shfl_xor(si, m, 64);
    sj += __shfl_xor(sj, m, 64);
    dp += __shfl_xor(dp, m, 64);
  }
  float ii = 1.0f / fmaxf(sqrtf(si), 1e-12f);
  float ij = 1.0f / fmaxf(sqrtf(sj), 1e-12f);
  if (lane == 0) pos[b] = dp * ii * ij;

  ushort_t* ri = reps + (size_t)b * DIM;
  ushort_t* rj = reps + (size_t)(b + N_ROWS) * DIM;
  store4bf(ri + lane * 4,       a0, ii);
  store4bf(ri + 256 + lane * 4, a1, ii);
  store4bf(rj + lane * 4,       b0, ij);
  store4bf(rj + 256 + lane * 4, b1, ij);
}

// ---------------------------------------------------------------------------
// Kernel 2: 256x256-tile fused sim-GEMM + exp + masked row/col reduction.
// Round-2 post-mortem: halving staged bytes left dur flat -> staging was
// L3-service-bound (~7 TB/s) because each XCD's resident blocks cycled
// through up to 8 MB of panels vs its 4 MB private L2.
// This round: SUPER-TILE BLOB ORDER. The 32x32 tile-triangle is split into
// 8x8 super-tiles (panel footprint 2-4 MB = fits one XCD L2). Tiles are
// ordered super-major; the chunked XCD remap (66 consecutive logical ids
// per XCD) then keeps each XCD's resident blocks inside ~1 super ->
// staging becomes an L2 hit. Diagonal tiles alias B onto As (skip B stage).
// ---------------------------------------------------------------------------
__global__ __launch_bounds__(512, 2) void sim_kernel(
    const ushort_t* __restrict__ reps, float* __restrict__ denom) {
  // chunked XCD remap: hardware XCD = blockIdx%8 -> XCD x owns logical ids
  // [x*66, (x+1)*66)
  int id = blockIdx.x;
  id = (id & 7) * (NB / 8) + (id >> 3);

  // super-tile blob decode: supers (si,sj), sj-major, si<=sj; diag super =
  // 36 tiles (8x8 triangle), off-diag = 64 (8x8 full)
  int bi, bj;
  {
    int rem = id, si = 0, sj = 0, found = 0;
    for (int s_j = 0; s_j < 4 && !found; ++s_j)
      for (int s_i = 0; s_i <= s_j && !found; ++s_i) {
        int sz = (s_i == s_j) ? 36 : 64;
        if (rem < sz) { si = s_i; sj = s_j; found = 1; }
        else rem -= sz;
      }
    if (si == sj) {
      int tj = 0;
      while ((tj + 1) * (tj + 2) / 2 <= rem) ++tj;   // tj <= 7
      int ti = rem - tj * (tj + 1) / 2;
      bi = si * 8 + ti;
      bj = sj * 8 + tj;
    } else {
      bi = si * 8 + (rem & 7);
      bj = sj * 8 + (rem >> 3);
    }
  }
  bool diag = (bi == bj);

  // [dbuf][half(128 rows)][128*64 bf16] ; 64 KB + 64 KB = 128 KB
  __shared__ ushort_t As[2][2][128 * 64];
  __shared__ ushort_t Bs[2][2][128 * 64];

  int tid  = threadIdx.x;
  int wave = tid >> 6, lane = tid & 63;
  int wr = wave >> 2, wc = wave & 3;       // 2 x 4 wave grid
  int hb = wc >> 1;                        // B half this wave consumes
  int q = lane >> 4, l15 = lane & 15;

  // ---- staging map: chunk (wave) covers rows wave*8..+7 of each half ----
  int srow = lane >> 3;                        // row within 8-row chunk
  int scol = ((lane & 7) ^ srow) * 8;          // pre-swizzled global col (elems)
  const ushort_t* pA0 = reps + (size_t)(bi * 256 + wave * 8 + srow) * DIM + scol;
  const ushort_t* pA1 = pA0 + (size_t)128 * DIM;
  const ushort_t* pB0 = reps + (size_t)(bj * 256 + wave * 8 + srow) * DIM + scol;
  const ushort_t* pB1 = pB0 + (size_t)128 * DIM;

#define STAGE_A(D, KOFF) do {                                      \
    ushort_t* la0 = &As[D][0][wave * 512];                         \
    ushort_t* la1 = &As[D][1][wave * 512];                         \
    async16(pA0 + (KOFF),            la0);                         \
    async16(pA0 + 64 * DIM + (KOFF), la0 + 4096);                  \
    async16(pA1 + (KOFF),            la1);                         \
    async16(pA1 + 64 * DIM + (KOFF), la1 + 4096);                  \
  } while (0)

#define STAGE_B(D, KOFF) do {                                      \
    ushort_t* lb0 = &Bs[D][0][wave * 512];                         \
    ushort_t* lb1 = &Bs[D][1][wave * 512];                         \
    async16(pB0 + (KOFF),            lb0);                         \
    async16(pB0 + 64 * DIM + (KOFF), lb0 + 4096);                  \
    async16(pB1 + (KOFF),            lb1);                         \
    async16(pB1 + 64 * DIM + (KOFF), lb1 + 4096);                  \
  } while (0)

  // ---- fragment read offsets (elems), swizzle slot ^= (row&7) ----
  int axor = l15 & 7;
  int aoff0 = l15 * 64 + ((q ^ axor) * 8);          // ks = 0
  int aoff1 = l15 * 64 + (((4 + q) ^ axor) * 8);    // ks = 1
  int boff0 = (wc & 1) * 4096 + aoff0;
  int boff1 = (wc & 1) * 4096 + aoff1;

  f32x4 zero4 = {0.0f, 0.0f, 0.0f, 0.0f};
  f32x4 acc[8][4];
#pragma unroll
  for (int m = 0; m < 8; ++m)
#pragma unroll
    for (int n = 0; n < 4; ++n) acc[m][n] = zero4;

#define READ_A(DST, MB) do {                                       \
    DST[0][0] = *(const short8*)(Ah + (MB) * 1024 + aoff0);        \
    DST[0][1] = *(const short8*)(Ah + (MB) * 1024 + aoff1);        \
    DST[1][0] = *(const short8*)(Ah + (MB + 1) * 1024 + aoff0);    \
    DST[1][1] = *(const short8*)(Ah + (MB + 1) * 1024 + aoff1);    \
  } while (0)

#define MFMA_PH(MB, AF) do {                                                          \
    _Pragma("unroll")                                                                 \
    for (int n = 0; n < 4; ++n) {                                                     \
      acc[MB][n] = __builtin_amdgcn_mfma_f32_16x16x32_bf16(                           \
          AF[0][0], bfr[0][n], acc[MB][n], 0, 0, 0);                                  \
      acc[MB][n] = __builtin_amdgcn_mfma_f32_16x16x32_bf16(                           \
          AF[0][1], bfr[1][n], acc[MB][n], 0, 0, 0);                                  \
      acc[MB + 1][n] = __builtin_amdgcn_mfma_f32_16x16x32_bf16(                       \
          AF[1][0], bfr[0][n], acc[MB + 1][n], 0, 0, 0);                              \
      acc[MB + 1][n] = __builtin_amdgcn_mfma_f32_16x16x32_bf16(                       \
          AF[1][1], bfr[1][n], acc[MB + 1][n], 0, 0, 0);                              \
    }                                                                                 \
  } while (0)

  // prologue: stage K-tile 0
  STAGE_A(0, 0);
  if (!diag) STAGE_B(0, 0);
  asm volatile("s_waitcnt vmcnt(0)" ::: "memory");
  __builtin_amdgcn_s_barrier();

  for (int kt = 0; kt < NKT; ++kt) {
    int cur = kt & 1;
    const ushort_t* Ah = &As[cur][wr][0];
    const ushort_t* Bh = diag ? &As[cur][hb][0] : &Bs[cur][hb][0];

    if (kt < NKT - 1) {
      STAGE_A(cur ^ 1, (kt + 1) * 64);
      if (!diag) STAGE_B(cur ^ 1, (kt + 1) * 64);
    }

    short8 bfr[2][4];
#pragma unroll
    for (int n = 0; n < 4; ++n) {
      bfr[0][n] = *(const short8*)(Bh + n * 1024 + boff0);
      bfr[1][n] = *(const short8*)(Bh + n * 1024 + boff1);
    }
    short8 aX[2][2], aY[2][2];
    READ_A(aX, 0);
    READ_A(aY, 2);

    __builtin_amdgcn_s_barrier();
    __builtin_amdgcn_s_setprio(1);
    MFMA_PH(0, aX);
    __builtin_amdgcn_s_setprio(0);
    READ_A(aX, 4);

    __builtin_amdgcn_s_barrier();
    __builtin_amdgcn_s_setprio(1);
    MFMA_PH(2, aY);
    __builtin_amdgcn_s_setprio(0);
    READ_A(aY, 6);

    __builtin_amdgcn_s_barrier();
    __builtin_amdgcn_s_setprio(1);
    MFMA_PH(4, aX);
    __builtin_amdgcn_s_setprio(0);

    __builtin_amdgcn_s_barrier();
    __builtin_amdgcn_s_setprio(1);
    MFMA_PH(6, aY);
    __builtin_amdgcn_s_setprio(0);

    // tile boundary: next tile's staging (issued a full tile of MFMA ago)
    // must be LDS-visible to all waves before anyone reads it
    asm volatile("s_waitcnt vmcnt(0)" ::: "memory");
    __builtin_amdgcn_s_barrier();
  }

  // ---- epilogue: e = exp(sim/T), mask diagonal, row + col sums ----
  // C layout per 16x16 frag: col = l15, row = q*4 + r  [m89/m91]
  int rowb = bi * 256 + wr * 128 + q * 4;   // + m*16 + r
  int colb = bj * 256 + wc * 64 + l15;      // + n*16

  float rsum[8][4];
  float csum[4] = {0.0f, 0.0f, 0.0f, 0.0f};
#pragma unroll
  for (int m = 0; m < 8; ++m)
#pragma unroll
    for (int r = 0; r < 4; ++r) rsum[m][r] = 0.0f;

#pragma unroll
  for (int m = 0; m < 8; ++m) {
#pragma unroll
    for (int n = 0; n < 4; ++n) {
      f32x4 a = acc[m][n];
#pragma unroll
      for (int r = 0; r < 4; ++r) {
        float v = exp2f(a[r] * EXP_SCALE);
        if (diag && (rowb + m * 16 + r) == (colb + n * 16)) v = 0.0f;
        rsum[m][r] += v;
        csum[n] += v;
      }
    }
  }

  // row sums: reduce across l15 (masks 1,2,4,8)
#pragma unroll
  for (int m = 0; m < 8; ++m)
#pragma unroll
    for (int r = 0; r < 4; ++r) {
      float v = rsum[m][r];
      v += __shfl_xor(v, 1, 64);
      v += __shfl_xor(v, 2, 64);
      v += __shfl_xor(v, 4, 64);
      v += __shfl_xor(v, 8, 64);
      if (l15 == 0) atomicAdd(&denom[rowb + m * 16 + r], v);
    }

  if (!diag) {
    // col sums: reduce across q (masks 16,32)
#pragma unroll
    for (int n = 0; n < 4; ++n) {
      float v = csum[n];
      v += __shfl_xor(v, 16, 64);
      v += __shfl_xor(v, 32, 64);
      if (q == 0) atomicAdd(&denom[colb + n * 16], v);
    }
  }
}

// ---------------------------------------------------------------------------
// Kernel 3: loss = mean over rows of [log(denom) - pos/T]
// ---------------------------------------------------------------------------
__global__ __launch_bounds__(256) void loss_kernel(
    const float* __restrict__ denom, const float* __restrict__ pos,
    float* __restrict__ out) {
  __shared__ float red[4];
  int tid = threadIdx.x;
  float p = 0.0f;
  for (int r = tid; r < M_ROWS; r += 256)
    p += logf(denom[r]) - pos[r & (N_ROWS - 1)] * 10.0f;
#pragma unroll
  for (int m = 32; m >= 1; m >>= 1) p += __shfl_xor(p, m, 64);
  if ((tid & 63) == 0) red[tid >> 6] = p;
  __syncthreads();
  if (tid == 0)
    out[0] = (red[0] + red[1] + red[2] + red[3]) * (1.0f / M_ROWS);
}

extern "C" void kernel_launch(void* const* d_in, const int* in_sizes, int n_in,
                              void* d_out, int out_size, void* d_ws, size_t ws_size,
                              hipStream_t stream) {
  const float* ei = (const float*)d_in[0];
  const float* ej = (const float*)d_in[1];
  float* out = (float*)d_out;

  char* ws = (char*)d_ws;
  ushort_t* reps = (ushort_t*)ws;                                   // 8 MB bf16
  float* denom = (float*)(ws + (size_t)M_ROWS * DIM * 2);           // 32 KB
  float* pos = (float*)(ws + (size_t)M_ROWS * DIM * 2 + M_ROWS * 4);// 16 KB

  norm_kernel<<<N_ROWS / 4, 256, 0, stream>>>(ei, ej, reps, pos, denom);
  sim_kernel<<<NB, 512, 0, stream>>>(reps, denom);
  loss_kernel<<<1, 256, 0, stream>>>(denom, pos, out);
}

// Round 4
// 143.924 us; speedup vs baseline: 1.0571x; 1.0348x over previous
//
#include <hip/hip_runtime.h>
#include <hip/hip_bf16.h>
#include <math.h>

#define N_ROWS 4096
#define DIM    512
#define M_ROWS 8192
// sim GEMM: 256x256 tiles, BK=64, 8 waves (2 M x 4 N), per-wave 128x64 output
#define NTILE  32            // 8192 / 256
#define NB     528           // 32*33/2 triangular tiles (528 % 8 == 0)
#define NKT    8             // 512 / 64
// exp(sim/0.1) = exp2(sim * 10*log2(e))
#define EXP_SCALE 14.4269504088896340736f

typedef unsigned short ushort_t;
typedef __attribute__((ext_vector_type(8))) short short8;
typedef __attribute__((ext_vector_type(4))) float f32x4;

__device__ __forceinline__ ushort_t f2bf(float x) {
  unsigned int bits = __float_as_uint(x);
  unsigned int lsb = (bits >> 16) & 1u;
  bits += 0x7fffu + lsb;
  return (ushort_t)(bits >> 16);
}

__device__ __forceinline__ void store4bf(ushort_t* p, float4 v, float s) {
  union { ushort_t u[4]; uint2 d; } pk;
  pk.u[0] = f2bf(v.x * s);
  pk.u[1] = f2bf(v.y * s);
  pk.u[2] = f2bf(v.z * s);
  pk.u[3] = f2bf(v.w * s);
  *(uint2*)p = pk.d;
}

// async global -> LDS, 16 B/lane (lds dest = wave-uniform base + lane*16)
__device__ __forceinline__ void async16(const ushort_t* g, ushort_t* l) {
  __builtin_amdgcn_global_load_lds(
      (const __attribute__((address_space(1))) void*)g,
      (__attribute__((address_space(3))) void*)l,
      16, 0, 0);
}

// ---------------------------------------------------------------------------
// Kernel 1: per-row L2 normalize; 256-thread blocks, one wave per row-pair.
// Also zeroes denom[].
// ---------------------------------------------------------------------------
__global__ __launch_bounds__(256) void norm_kernel(
    const float* __restrict__ ei, const float* __restrict__ ej,
    ushort_t* __restrict__ reps, float* __restrict__ pos,
    float* __restrict__ denom) {
  int wave = threadIdx.x >> 6;
  int lane = threadIdx.x & 63;
  int b = blockIdx.x * 4 + wave;
  if (lane == 0) {
    denom[b] = 0.0f;
    denom[b + N_ROWS] = 0.0f;
  }
  const float4* pi = (const float4*)(ei + (size_t)b * DIM);
  const float4* pj = (const float4*)(ej + (size_t)b * DIM);
  float4 a0 = pi[lane];
  float4 a1 = pi[lane + 64];
  float4 b0 = pj[lane];
  float4 b1 = pj[lane + 64];

  float si = a0.x*a0.x + a0.y*a0.y + a0.z*a0.z + a0.w*a0.w
           + a1.x*a1.x + a1.y*a1.y + a1.z*a1.z + a1.w*a1.w;
  float sj = b0.x*b0.x + b0.y*b0.y + b0.z*b0.z + b0.w*b0.w
           + b1.x*b1.x + b1.y*b1.y + b1.z*b1.z + b1.w*b1.w;
  float dp = a0.x*b0.x + a0.y*b0.y + a0.z*b0.z + a0.w*b0.w
           + a1.x*b1.x + a1.y*b1.y + a1.z*b1.z + a1.w*b1.w;

#pragma unroll
  for (int m = 32; m >= 1; m >>= 1) {
    si += __shfl_xor(si, m, 64);
    sj += __shfl_xor(sj, m, 64);
    dp += __shfl_xor(dp, m, 64);
  }
  float ii = 1.0f / fmaxf(sqrtf(si), 1e-12f);
  float ij = 1.0f / fmaxf(sqrtf(sj), 1e-12f);
  if (lane == 0) pos[b] = dp * ii * ij;

  ushort_t* ri = reps + (size_t)b * DIM;
  ushort_t* rj = reps + (size_t)(b + N_ROWS) * DIM;
  store4bf(ri + lane * 4,       a0, ii);
  store4bf(ri + 256 + lane * 4, a1, ii);
  store4bf(rj + lane * 4,       b0, ij);
  store4bf(rj + 256 + lane * 4, b1, ij);
}

// ---------------------------------------------------------------------------
// Kernel 2: 256x256-tile fused sim-GEMM + exp + masked row/col reduction.
// Round-3 post-mortem: traffic cuts (532->270 MB staged, HBM fetch 81->19 MB)
// left dur flat at ~75 us = the "2-phase vmcnt(0)-drain" structural ceiling
// (684 TF packed == m230's 682). The invariant cost was the vmcnt(0) drain
// at every K-tile boundary serializing staging behind compute.
// This round (T4): COUNTED vmcnt, never 0 in the main loop.
//   tile top:  STAGE_A(t+1) ; s_waitcnt vmcnt(4) ; s_barrier
//     -> the 4 allowed-outstanding are the just-issued A(t+1) loads, so this
//        confirms ALL of tile t's 8 stage loads (issued 3-4 phases ago)
//        while keeping the pipeline full. STAGE_B(t+1) issues mid-tile.
//   kt=7 issues wrapped dummy stages (never read) to keep counts uniform;
//   one vmcnt(0) after the loop protects LDS at endpgm.
// ---------------------------------------------------------------------------
__global__ __launch_bounds__(512, 2) void sim_kernel(
    const ushort_t* __restrict__ reps, float* __restrict__ denom) {
  // chunked XCD remap: XCD x owns logical ids [x*66, (x+1)*66)
  int id = blockIdx.x;
  id = (id & 7) * (NB / 8) + (id >> 3);

  // super-tile blob decode: supers (si,sj), sj-major, si<=sj; diag super =
  // 36 tiles (8x8 triangle), off-diag = 64 (8x8 full). Keeps each XCD's
  // resident blocks inside ~1 super -> staging is an L2 hit (FETCH 19 MB).
  int bi, bj;
  {
    int rem = id, si = 0, sj = 0, found = 0;
    for (int s_j = 0; s_j < 4 && !found; ++s_j)
      for (int s_i = 0; s_i <= s_j && !found; ++s_i) {
        int sz = (s_i == s_j) ? 36 : 64;
        if (rem < sz) { si = s_i; sj = s_j; found = 1; }
        else rem -= sz;
      }
    if (si == sj) {
      int tj = 0;
      while ((tj + 1) * (tj + 2) / 2 <= rem) ++tj;   // tj <= 7
      int ti = rem - tj * (tj + 1) / 2;
      bi = si * 8 + ti;
      bj = sj * 8 + tj;
    } else {
      bi = si * 8 + (rem & 7);
      bj = sj * 8 + (rem >> 3);
    }
  }
  bool diag = (bi == bj);

  // [dbuf][half(128 rows)][128*64 bf16] ; 64 KB + 64 KB = 128 KB
  __shared__ ushort_t As[2][2][128 * 64];
  __shared__ ushort_t Bs[2][2][128 * 64];

  int tid  = threadIdx.x;
  int wave = tid >> 6, lane = tid & 63;
  int wr = wave >> 2, wc = wave & 3;       // 2 x 4 wave grid
  int hb = wc >> 1;                        // B half this wave consumes
  int q = lane >> 4, l15 = lane & 15;

  // ---- staging map: chunk (wave) covers rows wave*8..+7 of each half ----
  int srow = lane >> 3;                        // row within 8-row chunk
  int scol = ((lane & 7) ^ srow) * 8;          // pre-swizzled global col (elems)
  const ushort_t* pA0 = reps + (size_t)(bi * 256 + wave * 8 + srow) * DIM + scol;
  const ushort_t* pA1 = pA0 + (size_t)128 * DIM;
  const ushort_t* pB0 = reps + (size_t)(bj * 256 + wave * 8 + srow) * DIM + scol;
  const ushort_t* pB1 = pB0 + (size_t)128 * DIM;

#define STAGE_A(D, KOFF) do {                                      \
    ushort_t* la0 = &As[D][0][wave * 512];                         \
    ushort_t* la1 = &As[D][1][wave * 512];                         \
    async16(pA0 + (KOFF),            la0);                         \
    async16(pA0 + 64 * DIM + (KOFF), la0 + 4096);                  \
    async16(pA1 + (KOFF),            la1);                         \
    async16(pA1 + 64 * DIM + (KOFF), la1 + 4096);                  \
  } while (0)

#define STAGE_B(D, KOFF) do {                                      \
    ushort_t* lb0 = &Bs[D][0][wave * 512];                         \
    ushort_t* lb1 = &Bs[D][1][wave * 512];                         \
    async16(pB0 + (KOFF),            lb0);                         \
    async16(pB0 + 64 * DIM + (KOFF), lb0 + 4096);                  \
    async16(pB1 + (KOFF),            lb1);                         \
    async16(pB1 + 64 * DIM + (KOFF), lb1 + 4096);                  \
  } while (0)

  // ---- fragment read offsets (elems), swizzle slot ^= (row&7) ----
  int axor = l15 & 7;
  int aoff0 = l15 * 64 + ((q ^ axor) * 8);          // ks = 0
  int aoff1 = l15 * 64 + (((4 + q) ^ axor) * 8);    // ks = 1
  int boff0 = (wc & 1) * 4096 + aoff0;
  int boff1 = (wc & 1) * 4096 + aoff1;

  f32x4 zero4 = {0.0f, 0.0f, 0.0f, 0.0f};
  f32x4 acc[8][4];
#pragma unroll
  for (int m = 0; m < 8; ++m)
#pragma unroll
    for (int n = 0; n < 4; ++n) acc[m][n] = zero4;

#define READ_A(DST, MB) do {                                       \
    DST[0][0] = *(const short8*)(Ah + (MB) * 1024 + aoff0);        \
    DST[0][1] = *(const short8*)(Ah + (MB) * 1024 + aoff1);        \
    DST[1][0] = *(const short8*)(Ah + (MB + 1) * 1024 + aoff0);    \
    DST[1][1] = *(const short8*)(Ah + (MB + 1) * 1024 + aoff1);    \
  } while (0)

#define MFMA_PH(MB, AF) do {                                                          \
    _Pragma("unroll")                                                                 \
    for (int n = 0; n < 4; ++n) {                                                     \
      acc[MB][n] = __builtin_amdgcn_mfma_f32_16x16x32_bf16(                           \
          AF[0][0], bfr[0][n], acc[MB][n], 0, 0, 0);                                  \
      acc[MB][n] = __builtin_amdgcn_mfma_f32_16x16x32_bf16(                           \
          AF[0][1], bfr[1][n], acc[MB][n], 0, 0, 0);                                  \
      acc[MB + 1][n] = __builtin_amdgcn_mfma_f32_16x16x32_bf16(                       \
          AF[1][0], bfr[0][n], acc[MB + 1][n], 0, 0, 0);                              \
      acc[MB + 1][n] = __builtin_amdgcn_mfma_f32_16x16x32_bf16(                       \
          AF[1][1], bfr[1][n], acc[MB + 1][n], 0, 0, 0);                              \
    }                                                                                 \
  } while (0)

  // prologue: stage K-tile 0 (loop-top counted wait handles the drain)
  STAGE_A(0, 0);
  if (!diag) STAGE_B(0, 0);

  for (int kt = 0; kt < NKT; ++kt) {
    int cur = kt & 1;
    int nk = ((kt + 1) & 7) * 64;   // wrap at kt=7: dummy stage, never read
    const ushort_t* Ah = &As[cur][wr][0];
    const ushort_t* Bh = diag ? &As[cur][hb][0] : &Bs[cur][hb][0];

    // issue next tile's A-stages FIRST, then a counted wait: the 4 allowed
    // outstanding are exactly these new loads -> all of tile kt's staging
    // (A issued at top of kt-1, B mid kt-1) is confirmed without draining.
    STAGE_A(cur ^ 1, nk);
    asm volatile("s_waitcnt vmcnt(4)" ::: "memory");
    __builtin_amdgcn_s_barrier();   // cross-wave: buf[cur] fully valid

    short8 bfr[2][4];
#pragma unroll
    for (int n = 0; n < 4; ++n) {
      bfr[0][n] = *(const short8*)(Bh + n * 1024 + boff0);
      bfr[1][n] = *(const short8*)(Bh + n * 1024 + boff1);
    }
    short8 aX[2][2], aY[2][2];
    READ_A(aX, 0);
    READ_A(aY, 2);

    __builtin_amdgcn_s_setprio(1);
    MFMA_PH(0, aX);
    __builtin_amdgcn_s_setprio(0);
    READ_A(aX, 4);
    if (!diag) STAGE_B(cur ^ 1, nk);
    __builtin_amdgcn_s_barrier();

    __builtin_amdgcn_s_setprio(1);
    MFMA_PH(2, aY);
    __builtin_amdgcn_s_setprio(0);
    READ_A(aY, 6);
    __builtin_amdgcn_s_barrier();

    __builtin_amdgcn_s_setprio(1);
    MFMA_PH(4, aX);
    __builtin_amdgcn_s_setprio(0);
    __builtin_amdgcn_s_barrier();

    __builtin_amdgcn_s_setprio(1);
    MFMA_PH(6, aY);
    __builtin_amdgcn_s_setprio(0);
    __builtin_amdgcn_s_barrier();   // buf[cur] reads done before next STAGE_A
  }
  // drain the kt=7 dummy stages so no LDS-writing loads are in flight at end
  asm volatile("s_waitcnt vmcnt(0)" ::: "memory");

  // ---- epilogue: e = exp(sim/T), mask diagonal, row + col sums ----
  // C layout per 16x16 frag: col = l15, row = q*4 + r  [m89/m91]
  int rowb = bi * 256 + wr * 128 + q * 4;   // + m*16 + r
  int colb = bj * 256 + wc * 64 + l15;      // + n*16

  float rsum[8][4];
  float csum[4] = {0.0f, 0.0f, 0.0f, 0.0f};
#pragma unroll
  for (int m = 0; m < 8; ++m)
#pragma unroll
    for (int r = 0; r < 4; ++r) rsum[m][r] = 0.0f;

#pragma unroll
  for (int m = 0; m < 8; ++m) {
#pragma unroll
    for (int n = 0; n < 4; ++n) {
      f32x4 a = acc[m][n];
#pragma unroll
      for (int r = 0; r < 4; ++r) {
        float v = exp2f(a[r] * EXP_SCALE);
        if (diag && (rowb + m * 16 + r) == (colb + n * 16)) v = 0.0f;
        rsum[m][r] += v;
        csum[n] += v;
      }
    }
  }

  // row sums: reduce across l15 (masks 1,2,4,8)
#pragma unroll
  for (int m = 0; m < 8; ++m)
#pragma unroll
    for (int r = 0; r < 4; ++r) {
      float v = rsum[m][r];
      v += __shfl_xor(v, 1, 64);
      v += __shfl_xor(v, 2, 64);
      v += __shfl_xor(v, 4, 64);
      v += __shfl_xor(v, 8, 64);
      if (l15 == 0) atomicAdd(&denom[rowb + m * 16 + r], v);
    }

  if (!diag) {
    // col sums: reduce across q (masks 16,32)
#pragma unroll
    for (int n = 0; n < 4; ++n) {
      float v = csum[n];
      v += __shfl_xor(v, 16, 64);
      v += __shfl_xor(v, 32, 64);
      if (q == 0) atomicAdd(&denom[colb + n * 16], v);
    }
  }
}

// ---------------------------------------------------------------------------
// Kernel 3: loss = mean over rows of [log(denom) - pos/T]
// ---------------------------------------------------------------------------
__global__ __launch_bounds__(256) void loss_kernel(
    const float* __restrict__ denom, const float* __restrict__ pos,
    float* __restrict__ out) {
  __shared__ float red[4];
  int tid = threadIdx.x;
  float p = 0.0f;
  for (int r = tid; r < M_ROWS; r += 256)
    p += logf(denom[r]) - pos[r & (N_ROWS - 1)] * 10.0f;
#pragma unroll
  for (int m = 32; m >= 1; m >>= 1) p += __shfl_xor(p, m, 64);
  if ((tid & 63) == 0) red[tid >> 6] = p;
  __syncthreads();
  if (tid == 0)
    out[0] = (red[0] + red[1] + red[2] + red[3]) * (1.0f / M_ROWS);
}

extern "C" void kernel_launch(void* const* d_in, const int* in_sizes, int n_in,
                              void* d_out, int out_size, void* d_ws, size_t ws_size,
                              hipStream_t stream) {
  const float* ei = (const float*)d_in[0];
  const float* ej = (const float*)d_in[1];
  float* out = (float*)d_out;

  char* ws = (char*)d_ws;
  ushort_t* reps = (ushort_t*)ws;                                   // 8 MB bf16
  float* denom = (float*)(ws + (size_t)M_ROWS * DIM * 2);           // 32 KB
  float* pos = (float*)(ws + (size_t)M_ROWS * DIM * 2 + M_ROWS * 4);// 16 KB

  norm_kernel<<<N_ROWS / 4, 256, 0, stream>>>(ei, ej, reps, pos, denom);
  sim_kernel<<<NB, 512, 0, stream>>>(reps, denom);
  loss_kernel<<<1, 256, 0, stream>>>(denom, pos, out);
}